// Round 1
// baseline (433.863 us; speedup 1.0000x reference)
//
#include <hip/hip_runtime.h>
#include <math.h>

namespace {
constexpr int kB = 4;
constexpr int kL = 4096;
constexpr int kH = 16;
constexpr int kD = 64;
constexpr int kM = 4096;          // complex FFT length (rfft of 8192 via packing)
constexpr int kStride = kH * kD;  // 1024 floats between consecutive l
constexpr int NTH = 256;

__device__ __forceinline__ float2 cmul(float2 a, float2 b) {
  return make_float2(a.x * b.x - a.y * b.y, a.x * b.y + a.y * b.x);
}
__device__ __forceinline__ float2 cadd(float2 a, float2 b) { return make_float2(a.x + b.x, a.y + b.y); }
__device__ __forceinline__ float2 csub(float2 a, float2 b) { return make_float2(a.x - b.x, a.y - b.y); }
__device__ __forceinline__ float2 cconj(float2 a) { return make_float2(a.x, -a.y); }
__device__ __forceinline__ float2 cmuli(float2 a) { return make_float2(-a.y, a.x); }  // i*a
__device__ __forceinline__ float2 cscale(float2 a, float s) { return make_float2(a.x * s, a.y * s); }

// base-4 digit reversal of a 12-bit index
__device__ __forceinline__ unsigned dr4(unsigned p) {
  unsigned r = __brev(p) >> 20;
  return ((r & 0x555u) << 1) | ((r >> 1) & 0x555u);
}

// filt[k] = amp * (1 + i k)^(-dec), with 1/M ifft scale folded into ampS
__device__ __forceinline__ float2 filt_val(float k, float ampS, float dec) {
  float mag = ampS * __expf(-0.5f * dec * log1pf(k * k));
  float ph = -dec * atanf(k);
  float s, c;
  __sincosf(ph, &s, &c);
  return make_float2(mag * c, mag * s);
}
}  // namespace

__global__ __launch_bounds__(NTH) void fftconv_kernel(
    const float* __restrict__ x, const float* __restrict__ log_amp,
    const float* __restrict__ log_decay, const float* __restrict__ mix_logit,
    float* __restrict__ out) {
  __shared__ float2 Z[kM];  // 32 KB
  const int row = blockIdx.x;
  const int d = row & (kD - 1);
  const int h = (row >> 6) & (kH - 1);
  const int b = row >> 10;
  const int t = threadIdx.x;
  const size_t rowoff = (size_t)b * kL * kStride + (size_t)h * kD + (size_t)d;
  const float* xrow = x + rowoff;
  float* orow = out + rowoff;

  // per-head params (uniform across block)
  const float av = log_amp[h];
  const float dv = log_decay[h];
  const float amp = (av > 20.f) ? av : log1pf(__expf(av));
  const float dec = ((dv > 20.f) ? dv : log1pf(__expf(dv))) + 1e-4f;
  const float ampS = amp * (1.0f / (float)kM);  // fold 1/M inverse-FFT scale
  const float ml = mix_logit[h];
  const float mix = 1.0f / (1.0f + __expf(-ml));
  const float omix = 1.0f - mix;

  // ---- load + pack: z[n] = x[2n] + i x[2n+1]; upper half zero (padding) ----
  for (int i = 0; i < kM / NTH; ++i) {
    int n = t + i * NTH;
    float2 z;
    if (n < kL / 2) {
      z.x = xrow[(size_t)(2 * n) * kStride];
      z.y = xrow[(size_t)(2 * n + 1) * kStride];
    } else {
      z = make_float2(0.f, 0.f);
    }
    Z[n] = z;
  }
  __syncthreads();

  // ---- forward FFT: in-place radix-4 DIF (digit-reversed output) ----
  for (int Ls = kM; Ls >= 4; Ls >>= 2) {
    const int q = Ls >> 2;
    const float wstep = -6.283185307179586f / (float)Ls;
    for (int i = 0; i < kM / 4 / NTH; ++i) {
      int bt = t + i * NTH;
      int jj = bt & (q - 1);
      int base = ((bt - jj) << 2) + jj;
      float2 a = Z[base], bb = Z[base + q], c = Z[base + 2 * q], dd = Z[base + 3 * q];
      float2 t0 = cadd(a, c), t1 = csub(a, c), t2 = cadd(bb, dd), t3 = csub(bb, dd);
      float2 u0 = cadd(t0, t2), u2 = csub(t0, t2);
      float2 it3 = cmuli(t3);
      float2 u1 = csub(t1, it3), u3 = cadd(t1, it3);
      float sn, cs;
      __sincosf(wstep * (float)jj, &sn, &cs);
      float2 w1 = make_float2(cs, sn);
      float2 w2 = cmul(w1, w1);
      float2 w3 = cmul(w2, w1);
      Z[base] = u0;
      Z[base + q] = cmul(u1, w1);
      Z[base + 2 * q] = cmul(u2, w2);
      Z[base + 3 * q] = cmul(u3, w3);
    }
    __syncthreads();
  }

  // ---- pointwise: unpack rfft bins, apply filter, repack for inverse ----
  // position p holds bin dr4(p); thread owning k handles pair (k, M-k).
  for (int i = 0; i <= kM / 2 / NTH; ++i) {
    int k = t + i * NTH;
    if (k > kM / 2) continue;
    if (k == 0) {
      float2 Z0 = Z[0];
      float X0 = Z0.x + Z0.y;  // rfft bin 0 (real)
      float XM = Z0.x - Z0.y;  // rfft bin N/2 (real)
      float2 f0 = filt_val(0.f, ampS, dec);
      float2 fM = filt_val((float)kM, ampS, dec);
      float Y0 = X0 * f0.x;          // irfft uses only Re of bin 0
      float YM = XM * fM.x;          // irfft uses only Re of bin N/2
      Z[0] = make_float2(0.5f * (Y0 + YM), 0.5f * (Y0 - YM));  // W[0] = E0 + i O0
    } else if (k == kM / 2) {
      unsigned p = dr4(kM / 2);
      float2 Zk = Z[p];
      float2 f = filt_val((float)(kM / 2), ampS, dec);
      float2 Y = cmul(cconj(Zk), f);  // X[M/2] = conj(Z[M/2])
      Z[p] = cconj(Y);                // W[M/2] = conj(Y)
    } else {
      unsigned pk = dr4((unsigned)k), pmk = dr4((unsigned)(kM - k));
      float2 Zk = Z[pk], Zmk = Z[pmk];
      float2 A = cscale(cadd(Zk, cconj(Zmk)), 0.5f);
      float2 Bv = cscale(csub(Zk, cconj(Zmk)), 0.5f);
      float sn, cs;
      __sincosf(-3.14159265358979323846f * (float)k / (float)kM, &sn, &cs);
      float2 tw = make_float2(cs, sn);  // e^{-i pi k / M}
      float2 P = cmuli(cmul(tw, Bv));
      float2 Xk = csub(A, P);            // rfft bin k
      float2 Xmk = cconj(cadd(A, P));    // rfft bin M-k
      float2 Yk = cmul(Xk, filt_val((float)k, ampS, dec));
      float2 Ymk = cmul(Xmk, filt_val((float)(kM - k), ampS, dec));
      float2 Ev = cscale(cadd(Yk, cconj(Ymk)), 0.5f);
      float2 Ov = cscale(cmul(cconj(tw), csub(Yk, cconj(Ymk))), 0.5f);
      float2 iO = cmuli(Ov);
      Z[pk] = cadd(Ev, iO);            // W[k]
      Z[pmk] = cconj(csub(Ev, iO));    // W[M-k]
    }
  }
  __syncthreads();

  // ---- inverse FFT: radix-4 DIT (digit-reversed input -> natural output) ----
  for (int Ls = 4; Ls <= kM; Ls <<= 2) {
    const int q = Ls >> 2;
    const float wstep = 6.283185307179586f / (float)Ls;
    for (int i = 0; i < kM / 4 / NTH; ++i) {
      int bt = t + i * NTH;
      int jj = bt & (q - 1);
      int base = ((bt - jj) << 2) + jj;
      float sn, cs;
      __sincosf(wstep * (float)jj, &sn, &cs);
      float2 w1 = make_float2(cs, sn);
      float2 w2 = cmul(w1, w1);
      float2 w3 = cmul(w2, w1);
      float2 a = Z[base];
      float2 bb = cmul(Z[base + q], w1);
      float2 c = cmul(Z[base + 2 * q], w2);
      float2 dd = cmul(Z[base + 3 * q], w3);
      float2 s0 = cadd(a, c), s1 = csub(a, c), s2 = cadd(bb, dd), s3 = csub(bb, dd);
      float2 is3 = cmuli(s3);
      Z[base] = cadd(s0, s2);
      Z[base + 2 * q] = csub(s0, s2);
      Z[base + q] = cadd(s1, is3);
      Z[base + 3 * q] = csub(s1, is3);
    }
    __syncthreads();
  }

  // ---- epilogue: y[2n]=Re w[n], y[2n+1]=Im w[n]; out = mix*y + (1-mix)*x ----
  for (int i = 0; i < kL / 2 / NTH; ++i) {
    int n = t + i * NTH;
    float2 w = Z[n];
    size_t i0 = (size_t)(2 * n) * kStride;
    float x0 = xrow[i0];
    float x1 = xrow[i0 + kStride];
    orow[i0] = mix * w.x + omix * x0;
    orow[i0 + kStride] = mix * w.y + omix * x1;
  }
}

extern "C" void kernel_launch(void* const* d_in, const int* in_sizes, int n_in,
                              void* d_out, int out_size, void* d_ws, size_t ws_size,
                              hipStream_t stream) {
  const float* x = (const float*)d_in[0];
  const float* la = (const float*)d_in[1];
  const float* ld = (const float*)d_in[2];
  const float* ml = (const float*)d_in[3];
  float* out = (float*)d_out;
  fftconv_kernel<<<dim3(kB * kH * kD), dim3(NTH), 0, stream>>>(x, la, ld, ml, out);
}

// Round 2
// 247.676 us; speedup vs baseline: 1.7517x; 1.7517x over previous
//
#include <hip/hip_runtime.h>
#include <math.h>

namespace {
constexpr int kB = 4;
constexpr int kL = 4096;
constexpr int kH = 16;
constexpr int kD = 64;
constexpr int kC = kH * kD;       // 1024 channels (h*64+d)
constexpr int kM = 4096;          // complex FFT length (rfft of 8192 via packing)
constexpr int NTH = 256;

__device__ __forceinline__ float2 cmul(float2 a, float2 b) {
  return make_float2(a.x * b.x - a.y * b.y, a.x * b.y + a.y * b.x);
}
__device__ __forceinline__ float2 cadd(float2 a, float2 b) { return make_float2(a.x + b.x, a.y + b.y); }
__device__ __forceinline__ float2 csub(float2 a, float2 b) { return make_float2(a.x - b.x, a.y - b.y); }
__device__ __forceinline__ float2 cconj(float2 a) { return make_float2(a.x, -a.y); }
__device__ __forceinline__ float2 cmuli(float2 a) { return make_float2(-a.y, a.x); }  // i*a
__device__ __forceinline__ float2 cscale(float2 a, float s) { return make_float2(a.x * s, a.y * s); }

// base-4 digit reversal of a 12-bit index
__device__ __forceinline__ unsigned dr4(unsigned p) {
  unsigned r = __brev(p) >> 20;
  return ((r & 0x555u) << 1) | ((r >> 1) & 0x555u);
}

// LDS anti-bank-conflict padding: one extra float2 every 16
__device__ __forceinline__ int IDX(int i) { return i + (i >> 4); }
constexpr int kZPad = kM + (kM >> 4);  // 4352 float2 = 34 KB

// filt[k] = amp * (1 + i k)^(-dec), with 1/M ifft scale folded into ampS
__device__ __forceinline__ float2 filt_val(float k, float ampS, float dec) {
  float mag = ampS * __expf(-0.5f * dec * log1pf(k * k));
  float ph = -dec * atanf(k);
  float s, c;
  __sincosf(ph, &s, &c);
  return make_float2(mag * c, mag * s);
}
}  // namespace

// ---------- pass 1: transpose x (B, L, C) -> ws (B, C, L), coalesced ----------
__global__ __launch_bounds__(256) void transpose_fwd(const float* __restrict__ in,
                                                     float* __restrict__ outp) {
  __shared__ float T[32][33];
  const int b = blockIdx.z;
  const int r0 = blockIdx.x * 32;  // l
  const int c0 = blockIdx.y * 32;  // c
  const float* ib = in + (size_t)b * kL * kC;
  float* ob = outp + (size_t)b * kC * kL;
  const int tx = threadIdx.x & 31, ty = threadIdx.x >> 5;
  for (int i = 0; i < 32; i += 8)
    T[ty + i][tx] = ib[(size_t)(r0 + ty + i) * kC + c0 + tx];
  __syncthreads();
  for (int i = 0; i < 32; i += 8)
    ob[(size_t)(c0 + ty + i) * kL + r0 + tx] = T[tx][ty + i];
}

// ---------- pass 2: per-row FFT conv, in-place in ws ----------
__global__ __launch_bounds__(NTH) void fft_rows(float* __restrict__ wsrow0,
                                                const float* __restrict__ log_amp,
                                                const float* __restrict__ log_decay) {
  __shared__ float2 Z[kZPad];
  const int row = blockIdx.x;           // b*1024 + c
  const int h = (row >> 6) & (kH - 1);
  const int t = threadIdx.x;
  float2* xrow = (float2*)(wsrow0 + (size_t)row * kL);

  const float av = log_amp[h];
  const float dv = log_decay[h];
  const float amp = (av > 20.f) ? av : log1pf(__expf(av));
  const float dec = ((dv > 20.f) ? dv : log1pf(__expf(dv))) + 1e-4f;
  const float ampS = amp * (1.0f / (float)kM);  // fold 1/M inverse-FFT scale

  // ---- load + pack: z[n] = x[2n] + i x[2n+1]; upper half zero (padding) ----
  for (int i = 0; i < kM / NTH; ++i) {
    int n = t + i * NTH;
    Z[IDX(n)] = (n < kL / 2) ? xrow[n] : make_float2(0.f, 0.f);
  }
  __syncthreads();

  // ---- forward FFT: in-place radix-4 DIF (digit-reversed output) ----
  for (int Ls = kM; Ls >= 4; Ls >>= 2) {
    const int q = Ls >> 2;
    const float wstep = -6.283185307179586f / (float)Ls;
    for (int i = 0; i < kM / 4 / NTH; ++i) {
      int bt = t + i * NTH;
      int jj = bt & (q - 1);
      int base = ((bt - jj) << 2) + jj;
      float2 a = Z[IDX(base)], bb = Z[IDX(base + q)];
      float2 c = Z[IDX(base + 2 * q)], dd = Z[IDX(base + 3 * q)];
      float2 t0 = cadd(a, c), t1 = csub(a, c), t2 = cadd(bb, dd), t3 = csub(bb, dd);
      float2 u0 = cadd(t0, t2), u2 = csub(t0, t2);
      float2 it3 = cmuli(t3);
      float2 u1 = csub(t1, it3), u3 = cadd(t1, it3);
      float sn, cs;
      __sincosf(wstep * (float)jj, &sn, &cs);
      float2 w1 = make_float2(cs, sn);
      float2 w2 = cmul(w1, w1);
      float2 w3 = cmul(w2, w1);
      Z[IDX(base)] = u0;
      Z[IDX(base + q)] = cmul(u1, w1);
      Z[IDX(base + 2 * q)] = cmul(u2, w2);
      Z[IDX(base + 3 * q)] = cmul(u3, w3);
    }
    __syncthreads();
  }

  // ---- pointwise: unpack rfft bins, apply filter, repack for inverse ----
  for (int i = 0; i <= kM / 2 / NTH; ++i) {
    int k = t + i * NTH;
    if (k > kM / 2) continue;
    if (k == 0) {
      float2 Z0 = Z[IDX(0)];
      float X0 = Z0.x + Z0.y;
      float XM = Z0.x - Z0.y;
      float2 f0 = filt_val(0.f, ampS, dec);
      float2 fM = filt_val((float)kM, ampS, dec);
      float Y0 = X0 * f0.x;
      float YM = XM * fM.x;
      Z[IDX(0)] = make_float2(0.5f * (Y0 + YM), 0.5f * (Y0 - YM));
    } else if (k == kM / 2) {
      unsigned p = dr4(kM / 2);
      float2 Zk = Z[IDX(p)];
      float2 f = filt_val((float)(kM / 2), ampS, dec);
      float2 Y = cmul(cconj(Zk), f);
      Z[IDX(p)] = cconj(Y);
    } else {
      unsigned pk = dr4((unsigned)k), pmk = dr4((unsigned)(kM - k));
      float2 Zk = Z[IDX(pk)], Zmk = Z[IDX(pmk)];
      float2 A = cscale(cadd(Zk, cconj(Zmk)), 0.5f);
      float2 Bv = cscale(csub(Zk, cconj(Zmk)), 0.5f);
      float sn, cs;
      __sincosf(-3.14159265358979323846f * (float)k / (float)kM, &sn, &cs);
      float2 tw = make_float2(cs, sn);  // e^{-i pi k / M}
      float2 P = cmuli(cmul(tw, Bv));
      float2 Xk = csub(A, P);
      float2 Xmk = cconj(cadd(A, P));
      float2 Yk = cmul(Xk, filt_val((float)k, ampS, dec));
      float2 Ymk = cmul(Xmk, filt_val((float)(kM - k), ampS, dec));
      float2 Ev = cscale(cadd(Yk, cconj(Ymk)), 0.5f);
      float2 Ov = cscale(cmul(cconj(tw), csub(Yk, cconj(Ymk))), 0.5f);
      float2 iO = cmuli(Ov);
      Z[IDX(pk)] = cadd(Ev, iO);
      Z[IDX(pmk)] = cconj(csub(Ev, iO));
    }
  }
  __syncthreads();

  // ---- inverse FFT: radix-4 DIT (digit-reversed input -> natural output) ----
  for (int Ls = 4; Ls <= kM; Ls <<= 2) {
    const int q = Ls >> 2;
    const float wstep = 6.283185307179586f / (float)Ls;
    for (int i = 0; i < kM / 4 / NTH; ++i) {
      int bt = t + i * NTH;
      int jj = bt & (q - 1);
      int base = ((bt - jj) << 2) + jj;
      float sn, cs;
      __sincosf(wstep * (float)jj, &sn, &cs);
      float2 w1 = make_float2(cs, sn);
      float2 w2 = cmul(w1, w1);
      float2 w3 = cmul(w2, w1);
      float2 a = Z[IDX(base)];
      float2 bb = cmul(Z[IDX(base + q)], w1);
      float2 c = cmul(Z[IDX(base + 2 * q)], w2);
      float2 dd = cmul(Z[IDX(base + 3 * q)], w3);
      float2 s0 = cadd(a, c), s1 = csub(a, c), s2 = cadd(bb, dd), s3 = csub(bb, dd);
      float2 is3 = cmuli(s3);
      Z[IDX(base)] = cadd(s0, s2);
      Z[IDX(base + 2 * q)] = csub(s0, s2);
      Z[IDX(base + q)] = cadd(s1, is3);
      Z[IDX(base + 3 * q)] = csub(s1, is3);
    }
    __syncthreads();
  }

  // ---- write back y (first kL samples) in-place, coalesced ----
  for (int i = 0; i < kL / 2 / NTH; ++i) {
    int n = t + i * NTH;
    xrow[n] = Z[IDX(n)];
  }
}

// ---------- pass 3: transpose back ws (B, C, L) -> out (B, L, C) + mix ----------
__global__ __launch_bounds__(256) void mix_out(const float* __restrict__ yT,
                                               const float* __restrict__ x,
                                               const float* __restrict__ mix_logit,
                                               float* __restrict__ outp) {
  __shared__ float T[32][33];
  const int b = blockIdx.z;
  const int r0 = blockIdx.x * 32;  // l
  const int c0 = blockIdx.y * 32;  // c
  const int h = c0 >> 6;           // uniform per block (32-wide chunk within 64-wide head)
  const float ml = mix_logit[h];
  const float mix = 1.0f / (1.0f + __expf(-ml));
  const float omix = 1.0f - mix;
  const float* yb = yT + (size_t)b * kC * kL;
  const float* xb = x + (size_t)b * kL * kC;
  float* ob = outp + (size_t)b * kL * kC;
  const int tx = threadIdx.x & 31, ty = threadIdx.x >> 5;
  for (int i = 0; i < 32; i += 8)
    T[ty + i][tx] = yb[(size_t)(c0 + ty + i) * kL + r0 + tx];
  __syncthreads();
  for (int i = 0; i < 32; i += 8) {
    size_t idx = (size_t)(r0 + ty + i) * kC + c0 + tx;
    ob[idx] = mix * T[tx][ty + i] + omix * xb[idx];
  }
}

// ---------- fallback (round-1 single kernel) if ws is too small ----------
__global__ __launch_bounds__(NTH) void fftconv_fallback(
    const float* __restrict__ x, const float* __restrict__ log_amp,
    const float* __restrict__ log_decay, const float* __restrict__ mix_logit,
    float* __restrict__ out) {
  __shared__ float2 Z[kZPad];
  const int row = blockIdx.x;
  const int d = row & (kD - 1);
  const int h = (row >> 6) & (kH - 1);
  const int b = row >> 10;
  const int t = threadIdx.x;
  const size_t rowoff = (size_t)b * kL * kC + (size_t)h * kD + (size_t)d;
  const float* xrow = x + rowoff;
  float* orow = out + rowoff;

  const float av = log_amp[h];
  const float dv = log_decay[h];
  const float amp = (av > 20.f) ? av : log1pf(__expf(av));
  const float dec = ((dv > 20.f) ? dv : log1pf(__expf(dv))) + 1e-4f;
  const float ampS = amp * (1.0f / (float)kM);
  const float ml = mix_logit[h];
  const float mix = 1.0f / (1.0f + __expf(-ml));
  const float omix = 1.0f - mix;

  for (int i = 0; i < kM / NTH; ++i) {
    int n = t + i * NTH;
    float2 z;
    if (n < kL / 2) {
      z.x = xrow[(size_t)(2 * n) * kC];
      z.y = xrow[(size_t)(2 * n + 1) * kC];
    } else {
      z = make_float2(0.f, 0.f);
    }
    Z[IDX(n)] = z;
  }
  __syncthreads();

  for (int Ls = kM; Ls >= 4; Ls >>= 2) {
    const int q = Ls >> 2;
    const float wstep = -6.283185307179586f / (float)Ls;
    for (int i = 0; i < kM / 4 / NTH; ++i) {
      int bt = t + i * NTH;
      int jj = bt & (q - 1);
      int base = ((bt - jj) << 2) + jj;
      float2 a = Z[IDX(base)], bb = Z[IDX(base + q)];
      float2 c = Z[IDX(base + 2 * q)], dd = Z[IDX(base + 3 * q)];
      float2 t0 = cadd(a, c), t1 = csub(a, c), t2 = cadd(bb, dd), t3 = csub(bb, dd);
      float2 u0 = cadd(t0, t2), u2 = csub(t0, t2);
      float2 it3 = cmuli(t3);
      float2 u1 = csub(t1, it3), u3 = cadd(t1, it3);
      float sn, cs;
      __sincosf(wstep * (float)jj, &sn, &cs);
      float2 w1 = make_float2(cs, sn);
      float2 w2 = cmul(w1, w1);
      float2 w3 = cmul(w2, w1);
      Z[IDX(base)] = u0;
      Z[IDX(base + q)] = cmul(u1, w1);
      Z[IDX(base + 2 * q)] = cmul(u2, w2);
      Z[IDX(base + 3 * q)] = cmul(u3, w3);
    }
    __syncthreads();
  }

  for (int i = 0; i <= kM / 2 / NTH; ++i) {
    int k = t + i * NTH;
    if (k > kM / 2) continue;
    if (k == 0) {
      float2 Z0 = Z[IDX(0)];
      float X0 = Z0.x + Z0.y;
      float XM = Z0.x - Z0.y;
      float2 f0 = filt_val(0.f, ampS, dec);
      float2 fM = filt_val((float)kM, ampS, dec);
      float Y0 = X0 * f0.x;
      float YM = XM * fM.x;
      Z[IDX(0)] = make_float2(0.5f * (Y0 + YM), 0.5f * (Y0 - YM));
    } else if (k == kM / 2) {
      unsigned p = dr4(kM / 2);
      float2 Zk = Z[IDX(p)];
      float2 f = filt_val((float)(kM / 2), ampS, dec);
      float2 Y = cmul(cconj(Zk), f);
      Z[IDX(p)] = cconj(Y);
    } else {
      unsigned pk = dr4((unsigned)k), pmk = dr4((unsigned)(kM - k));
      float2 Zk = Z[IDX(pk)], Zmk = Z[IDX(pmk)];
      float2 A = cscale(cadd(Zk, cconj(Zmk)), 0.5f);
      float2 Bv = cscale(csub(Zk, cconj(Zmk)), 0.5f);
      float sn, cs;
      __sincosf(-3.14159265358979323846f * (float)k / (float)kM, &sn, &cs);
      float2 tw = make_float2(cs, sn);
      float2 P = cmuli(cmul(tw, Bv));
      float2 Xk = csub(A, P);
      float2 Xmk = cconj(cadd(A, P));
      float2 Yk = cmul(Xk, filt_val((float)k, ampS, dec));
      float2 Ymk = cmul(Xmk, filt_val((float)(kM - k), ampS, dec));
      float2 Ev = cscale(cadd(Yk, cconj(Ymk)), 0.5f);
      float2 Ov = cscale(cmul(cconj(tw), csub(Yk, cconj(Ymk))), 0.5f);
      float2 iO = cmuli(Ov);
      Z[IDX(pk)] = cadd(Ev, iO);
      Z[IDX(pmk)] = cconj(csub(Ev, iO));
    }
  }
  __syncthreads();

  for (int Ls = 4; Ls <= kM; Ls <<= 2) {
    const int q = Ls >> 2;
    const float wstep = 6.283185307179586f / (float)Ls;
    for (int i = 0; i < kM / 4 / NTH; ++i) {
      int bt = t + i * NTH;
      int jj = bt & (q - 1);
      int base = ((bt - jj) << 2) + jj;
      float sn, cs;
      __sincosf(wstep * (float)jj, &sn, &cs);
      float2 w1 = make_float2(cs, sn);
      float2 w2 = cmul(w1, w1);
      float2 w3 = cmul(w2, w1);
      float2 a = Z[IDX(base)];
      float2 bb = cmul(Z[IDX(base + q)], w1);
      float2 c = cmul(Z[IDX(base + 2 * q)], w2);
      float2 dd = cmul(Z[IDX(base + 3 * q)], w3);
      float2 s0 = cadd(a, c), s1 = csub(a, c), s2 = cadd(bb, dd), s3 = csub(bb, dd);
      float2 is3 = cmuli(s3);
      Z[IDX(base)] = cadd(s0, s2);
      Z[IDX(base + 2 * q)] = csub(s0, s2);
      Z[IDX(base + q)] = cadd(s1, is3);
      Z[IDX(base + 3 * q)] = csub(s1, is3);
    }
    __syncthreads();
  }

  for (int i = 0; i < kL / 2 / NTH; ++i) {
    int n = t + i * NTH;
    float2 w = Z[IDX(n)];
    size_t i0 = (size_t)(2 * n) * kC;
    float x0 = xrow[i0];
    float x1 = xrow[i0 + kC];
    orow[i0] = mix * w.x + omix * x0;
    orow[i0 + kC] = mix * w.y + omix * x1;
  }
}

extern "C" void kernel_launch(void* const* d_in, const int* in_sizes, int n_in,
                              void* d_out, int out_size, void* d_ws, size_t ws_size,
                              hipStream_t stream) {
  const float* x = (const float*)d_in[0];
  const float* la = (const float*)d_in[1];
  const float* ld = (const float*)d_in[2];
  const float* ml = (const float*)d_in[3];
  float* out = (float*)d_out;
  const size_t needed = (size_t)kB * kC * kL * sizeof(float);  // 64 MiB
  if (ws_size >= needed) {
    float* ws = (float*)d_ws;
    transpose_fwd<<<dim3(kL / 32, kC / 32, kB), dim3(256), 0, stream>>>(x, ws);
    fft_rows<<<dim3(kB * kC), dim3(NTH), 0, stream>>>(ws, la, ld);
    mix_out<<<dim3(kL / 32, kC / 32, kB), dim3(256), 0, stream>>>(ws, x, ml, out);
  } else {
    fftconv_fallback<<<dim3(kB * kC), dim3(NTH), 0, stream>>>(x, la, ld, ml, out);
  }
}

// Round 3
// 164.381 us; speedup vs baseline: 2.6394x; 1.5067x over previous
//
#include <hip/hip_runtime.h>
#include <math.h>

namespace {
constexpr int kB = 4;
constexpr int kL = 4096;
constexpr int kH = 16;
constexpr int kD = 64;
constexpr int kC = kH * kD;       // 1024 channels
constexpr int kM = 4096;          // complex FFT length (rfft of 8192 via packing)
constexpr int NTH = 256;

__device__ __forceinline__ float2 cmul(float2 a, float2 b) {
  return make_float2(a.x * b.x - a.y * b.y, a.x * b.y + a.y * b.x);
}
__device__ __forceinline__ float2 cadd(float2 a, float2 b) { return make_float2(a.x + b.x, a.y + b.y); }
__device__ __forceinline__ float2 csub(float2 a, float2 b) { return make_float2(a.x - b.x, a.y - b.y); }
__device__ __forceinline__ float2 cconj(float2 a) { return make_float2(a.x, -a.y); }
__device__ __forceinline__ float2 cmuli(float2 a) { return make_float2(-a.y, a.x); }  // i*a
__device__ __forceinline__ float2 cscale(float2 a, float s) { return make_float2(a.x * s, a.y * s); }

// base-4 digit reversal of a 12-bit index (fallback kernel only)
__device__ __forceinline__ unsigned dr4(unsigned p) {
  unsigned r = __brev(p) >> 20;
  return ((r & 0x555u) << 1) | ((r >> 1) & 0x555u);
}
// base-16 digit reversal of a 12-bit index
__device__ __forceinline__ unsigned dr16(unsigned p) {
  return ((p & 15u) << 8) | (p & 0xF0u) | (p >> 8);
}
// LDS swizzle (float2 index space): XOR low4 with bits 4..7 -> all FFT exchange
// patterns conflict-free per 16-lane group
__device__ __forceinline__ int SW(int i) { return i ^ ((i >> 4) & 15); }
// after in-register DFT16, X[k] lives at register slot POS(k)
#define POS(k) ((((k) & 3) << 2) | ((k) >> 2))

// fallback-kernel padding
__device__ __forceinline__ int IDX(int i) { return i + (i >> 4); }
constexpr int kZPad = kM + (kM >> 4);

// filt[k] = amp * (1 + i k)^(-dec), with 1/M ifft scale folded into ampS
__device__ __forceinline__ float2 filt_val(float k, float ampS, float dec) {
  float mag = ampS * __expf(-0.5f * dec * log1pf(k * k));
  float ph = -dec * atanf(k);
  float s, c;
  __sincosf(ph, &s, &c);
  return make_float2(mag * c, mag * s);
}

// ---- fully-unrolled 16-point DFT in registers ----
// S = -1 forward, +1 inverse (unnormalized). HZ: inputs r[8..15] treated as 0.
// Output X[k] at slot POS(k).
template <int S, bool HZ>
__device__ __forceinline__ void fft16(float2 r[16]) {
  constexpr float C1 = 0.92387953251128674f;
  constexpr float S1 = 0.38268343236508978f;
  constexpr float R2 = 0.70710678118654752f;
  const float sg = (float)S;
  const float2 W1 = make_float2(C1, sg * S1);
  const float2 W2 = make_float2(R2, sg * R2);
  const float2 W3 = make_float2(S1, sg * C1);
  const float2 W6 = make_float2(-R2, sg * R2);
  const float2 W9 = make_float2(-C1, -sg * S1);
  // level 1: DFT4 over n1 on slots {n2, n2+4, n2+8, n2+12}; twiddle W16^{n2*k1};
  // store b[k1,n2] at slot n2 + 4*k1
#pragma unroll
  for (int n2 = 0; n2 < 4; ++n2) {
    float2 t0, t1, t2, t3;
    if (HZ) {
      t0 = r[n2]; t1 = r[n2]; t2 = r[n2 + 4]; t3 = r[n2 + 4];
    } else {
      float2 a0 = r[n2], a1 = r[n2 + 4], a2 = r[n2 + 8], a3 = r[n2 + 12];
      t0 = cadd(a0, a2); t1 = csub(a0, a2); t2 = cadd(a1, a3); t3 = csub(a1, a3);
    }
    float2 j3 = (S < 0) ? make_float2(t3.y, -t3.x) : make_float2(-t3.y, t3.x);  // S*i*t3
    float2 u0 = cadd(t0, t2);
    float2 u1 = cadd(t1, j3);
    float2 u2 = csub(t0, t2);
    float2 u3 = csub(t1, j3);
    if (n2 == 0) { r[0] = u0; r[4] = u1; r[8] = u2; r[12] = u3; }
    if (n2 == 1) { r[1] = u0; r[5] = cmul(u1, W1); r[9] = cmul(u2, W2); r[13] = cmul(u3, W3); }
    if (n2 == 2) {
      r[2] = u0; r[6] = cmul(u1, W2);
      r[10] = (S < 0) ? make_float2(u2.y, -u2.x) : make_float2(-u2.y, u2.x);  // * W16^4 = S*i
      r[14] = cmul(u3, W6);
    }
    if (n2 == 3) { r[3] = u0; r[7] = cmul(u1, W3); r[11] = cmul(u2, W6); r[15] = cmul(u3, W9); }
  }
  // level 2: DFT4 over n2 on slots {4s..4s+3}; X[k2*4+s] -> slot 4s+k2
#pragma unroll
  for (int s = 0; s < 4; ++s) {
    float2 b0 = r[4 * s], b1 = r[4 * s + 1], b2 = r[4 * s + 2], b3 = r[4 * s + 3];
    float2 t0 = cadd(b0, b2), t1 = csub(b0, b2), t2 = cadd(b1, b3), t3 = csub(b1, b3);
    float2 j3 = (S < 0) ? make_float2(t3.y, -t3.x) : make_float2(-t3.y, t3.x);
    r[4 * s] = cadd(t0, t2);
    r[4 * s + 1] = cadd(t1, j3);
    r[4 * s + 2] = csub(t0, t2);
    r[4 * s + 3] = csub(t1, j3);
  }
}

// pointwise pair map (verified round-1/2 algebra), used only by build_table
__device__ __forceinline__ void pw_pair(float2 Zk, float2 Zmk, int k, float ampS, float dec,
                                        float2* Wk, float2* Wmk) {
  float2 A = cscale(cadd(Zk, cconj(Zmk)), 0.5f);
  float2 Bv = cscale(csub(Zk, cconj(Zmk)), 0.5f);
  float sn, cs;
  __sincosf(-3.14159265358979323846f * (float)k / (float)kM, &sn, &cs);
  float2 tw = make_float2(cs, sn);
  float2 P = cmuli(cmul(tw, Bv));
  float2 Xk = csub(A, P);
  float2 Xmk = cconj(cadd(A, P));
  float2 Yk = cmul(Xk, filt_val((float)k, ampS, dec));
  float2 Ymk = cmul(Xmk, filt_val((float)(kM - k), ampS, dec));
  float2 Ev = cscale(cadd(Yk, cconj(Ymk)), 0.5f);
  float2 Ov = cscale(cmul(cconj(tw), csub(Yk, cconj(Ymk))), 0.5f);
  float2 iO = cmuli(Ov);
  *Wk = cadd(Ev, iO);
  *Wmk = cconj(csub(Ev, iO));
}
}  // namespace

// ---------- pass 0: per-(h,k) 2x2 complex coefficient table ----------
__global__ __launch_bounds__(256) void build_table(const float* __restrict__ la,
                                                   const float* __restrict__ ld,
                                                   float2* __restrict__ tab) {
  int k = blockIdx.x * 256 + threadIdx.x;  // 0..2047
  int h = blockIdx.y;
  float av = la[h], dv = ld[h];
  float amp = (av > 20.f) ? av : log1pf(__expf(av));
  float dec = ((dv > 20.f) ? dv : log1pf(__expf(dv))) + 1e-4f;
  float ampS = amp * (1.0f / (float)kM);
  float2* e = tab + ((size_t)h * 2048 + k) * 4;
  if (k == 0) {
    float F0 = filt_val(0.f, ampS, dec).x;
    float FM = filt_val((float)kM, ampS, dec).x;
    e[0] = make_float2(0.5f * (F0 + FM), 0.5f * (F0 - FM));  // (m00, m01)
    e[1] = make_float2(0.5f * (F0 - FM), 0.5f * (F0 + FM));  // (m10, m11)
    e[2] = cconj(filt_val((float)(kM / 2), ampS, dec));      // k=2048 single-bin coeff
    e[3] = make_float2(0.f, 0.f);
  } else {
    float2 a, b, g, d;
    pw_pair(make_float2(1.f, 0.f), make_float2(0.f, 0.f), k, ampS, dec, &a, &g);
    pw_pair(make_float2(0.f, 0.f), make_float2(1.f, 0.f), k, ampS, dec, &b, &d);
    e[0] = a; e[1] = b; e[2] = g; e[3] = d;
  }
}

// ---------- pass 1: transpose x (B, L, C) -> ws (B, C, L), coalesced ----------
__global__ __launch_bounds__(256) void transpose_fwd(const float* __restrict__ in,
                                                     float* __restrict__ outp) {
  __shared__ float T[32][33];
  const int b = blockIdx.z;
  const int r0 = blockIdx.x * 32;  // l
  const int c0 = blockIdx.y * 32;  // c
  const float* ib = in + (size_t)b * kL * kC;
  float* ob = outp + (size_t)b * kC * kL;
  const int tx = threadIdx.x & 31, ty = threadIdx.x >> 5;
  for (int i = 0; i < 32; i += 8)
    T[ty + i][tx] = ib[(size_t)(r0 + ty + i) * kC + c0 + tx];
  __syncthreads();
  for (int i = 0; i < 32; i += 8)
    ob[(size_t)(c0 + ty + i) * kL + r0 + tx] = T[tx][ty + i];
}

// ---------- pass 2: per-row FFT conv (16^3 register radix-16), in-place ----------
__global__ __launch_bounds__(NTH) void fft_rows(float* __restrict__ ws,
                                                const float2* __restrict__ tab) {
  __shared__ float2 Z[kM];  // exactly 32 KB
  const int row = blockIdx.x;  // b*1024 + c
  const int h = (row >> 6) & (kH - 1);
  const int t = threadIdx.x;
  float2* xrow = (float2*)(ws + (size_t)row * kL);  // 2048 float2

  float2 r[16];
  const int swt = t ^ ((t >> 4) & 15);

  // ---- F1: global load (coalesced), DFT16 over n1, twiddle W4096^{t*k1} ----
#pragma unroll
  for (int j = 0; j < 8; ++j) r[j] = xrow[t + 256 * j];
  fft16<-1, true>(r);
  {
    float sn, cs;
    __sincosf(-6.283185307179586f * (float)t / 4096.f, &sn, &cs);
    float2 w = make_float2(cs, sn), cur = w;
    r[POS(1)] = cmul(r[POS(1)], cur);
#pragma unroll
    for (int k1 = 2; k1 < 16; ++k1) { cur = cmul(cur, w); r[POS(k1)] = cmul(r[POS(k1)], cur); }
    float2* Zb = &Z[swt];
#pragma unroll
    for (int k1 = 0; k1 < 16; ++k1) Zb[k1 << 8] = r[POS(k1)];
  }
  __syncthreads();

  // ---- F2: DFT16 over m1 (stride 16), twiddle W256^{m2*j1} ----
  {
    const int g = t >> 4, m2 = t & 15;
    const int base = g << 8;
#pragma unroll
    for (int m1 = 0; m1 < 16; ++m1) r[m1] = Z[base + (m1 << 4) + (m2 ^ m1)];
    fft16<-1, false>(r);
    float sn, cs;
    __sincosf(-6.283185307179586f * (float)m2 / 256.f, &sn, &cs);
    float2 w = make_float2(cs, sn), cur = w;
    r[POS(1)] = cmul(r[POS(1)], cur);
#pragma unroll
    for (int j1 = 2; j1 < 16; ++j1) { cur = cmul(cur, w); r[POS(j1)] = cmul(r[POS(j1)], cur); }
#pragma unroll
    for (int j1 = 0; j1 < 16; ++j1) Z[base + (j1 << 4) + (m2 ^ j1)] = r[POS(j1)];
  }
  __syncthreads();

  // ---- F3: DFT16 over m2 (contiguous 16), no twiddle ----
  {
    const int g = t >> 4, j1 = t & 15;
    const int base = (g << 8) + (j1 << 4);
#pragma unroll
    for (int m2 = 0; m2 < 16; ++m2) r[m2] = Z[base + (m2 ^ j1)];
    fft16<-1, false>(r);
#pragma unroll
    for (int j2 = 0; j2 < 16; ++j2) Z[base + (j2 ^ j1)] = r[POS(j2)];
  }
  __syncthreads();

  // ---- pointwise via table; position p holds bin dr16(p) ----
  for (int i = 0; i < 16; ++i) {
    int p = t + (i << 8);
    unsigned k = dr16((unsigned)p);
    if (k > 2048u) continue;
    if (k == 0u) {  // p == 0
      const float4* tp = (const float4*)(tab + (size_t)h * 2048 * 4);
      float4 q0 = tp[0];
      float2 Z0 = Z[0];
      Z[0] = make_float2(q0.x * Z0.x + q0.y * Z0.y, q0.z * Z0.x + q0.w * Z0.y);
    } else if (k == 2048u) {  // p == 8
      const float4* tp = (const float4*)(tab + (size_t)h * 2048 * 4);
      float4 q1 = tp[1];
      int sp = SW(p);
      Z[sp] = cmul(Z[sp], make_float2(q1.x, q1.y));
    } else {
      int p2 = (int)dr16(4096u - k);
      int sp = SW(p), sp2 = SW(p2);
      float2 Zk = Z[sp], Zmk = Z[sp2];
      const float4* tp = (const float4*)(tab + ((size_t)h * 2048 + k) * 4);
      float4 q0 = tp[0], q1 = tp[1];
      float2 e0 = make_float2(q0.x, q0.y), e1 = make_float2(q0.z, q0.w);
      float2 e2 = make_float2(q1.x, q1.y), e3 = make_float2(q1.z, q1.w);
      Z[sp] = cadd(cmul(e0, Zk), cmul(e1, cconj(Zmk)));
      Z[sp2] = cadd(cmul(e2, cconj(Zk)), cmul(e3, Zmk));
    }
  }
  __syncthreads();

  // ---- I1: IDFT16 over j2 (contiguous 16), twiddle e^{+2pi i j1*m2/256} ----
  {
    const int k1 = t >> 4, j1 = t & 15;
    const int base = (k1 << 8) + (j1 << 4);
#pragma unroll
    for (int j2 = 0; j2 < 16; ++j2) r[j2] = Z[base + (j2 ^ j1)];
    fft16<1, false>(r);
    float sn, cs;
    __sincosf(6.283185307179586f * (float)j1 / 256.f, &sn, &cs);
    float2 w = make_float2(cs, sn), cur = w;
    r[POS(1)] = cmul(r[POS(1)], cur);
#pragma unroll
    for (int m2 = 2; m2 < 16; ++m2) { cur = cmul(cur, w); r[POS(m2)] = cmul(r[POS(m2)], cur); }
#pragma unroll
    for (int m2 = 0; m2 < 16; ++m2) Z[base + (m2 ^ j1)] = r[POS(m2)];
  }
  __syncthreads();

  // ---- I2: IDFT16 over j1 (stride 16), twiddle e^{+2pi i k1*(m1*16+m2)/4096} ----
  {
    const int k1 = t >> 4, m2 = t & 15;
#pragma unroll
    for (int j1 = 0; j1 < 16; ++j1) r[j1] = Z[(k1 << 8) + (j1 << 4) + (m2 ^ j1)];
    fft16<1, false>(r);
    float sn, cs;
    __sincosf(6.283185307179586f * (float)(k1 * m2) / 4096.f, &sn, &cs);
    float2 cur = make_float2(cs, sn);
    __sincosf(6.283185307179586f * (float)k1 / 256.f, &sn, &cs);
    float2 w = make_float2(cs, sn);
    r[POS(0)] = cmul(r[POS(0)], cur);
#pragma unroll
    for (int m1 = 1; m1 < 16; ++m1) { cur = cmul(cur, w); r[POS(m1)] = cmul(r[POS(m1)], cur); }
#pragma unroll
    for (int m1 = 0; m1 < 16; ++m1) Z[(k1 << 8) + (m1 << 4) + (m2 ^ m1)] = r[POS(m1)];
  }
  __syncthreads();

  // ---- I3: IDFT16 over k1 (stride 256), direct coalesced global store ----
  {
    float2* Zb = &Z[swt];
#pragma unroll
    for (int k1 = 0; k1 < 16; ++k1) r[k1] = Zb[k1 << 8];
    fft16<1, false>(r);
#pragma unroll
    for (int n1 = 0; n1 < 8; ++n1) xrow[(n1 << 8) + t] = r[POS(n1)];
  }
}

// ---------- pass 3: transpose back ws (B, C, L) -> out (B, L, C) + mix ----------
__global__ __launch_bounds__(256) void mix_out(const float* __restrict__ yT,
                                               const float* __restrict__ x,
                                               const float* __restrict__ mix_logit,
                                               float* __restrict__ outp) {
  __shared__ float T[32][33];
  const int b = blockIdx.z;
  const int r0 = blockIdx.x * 32;  // l
  const int c0 = blockIdx.y * 32;  // c
  const int h = c0 >> 6;
  const float ml = mix_logit[h];
  const float mix = 1.0f / (1.0f + __expf(-ml));
  const float omix = 1.0f - mix;
  const float* yb = yT + (size_t)b * kC * kL;
  const float* xb = x + (size_t)b * kL * kC;
  float* ob = outp + (size_t)b * kL * kC;
  const int tx = threadIdx.x & 31, ty = threadIdx.x >> 5;
  for (int i = 0; i < 32; i += 8)
    T[ty + i][tx] = yb[(size_t)(c0 + ty + i) * kL + r0 + tx];
  __syncthreads();
  for (int i = 0; i < 32; i += 8) {
    size_t idx = (size_t)(r0 + ty + i) * kC + c0 + tx;
    ob[idx] = mix * T[tx][ty + i] + omix * xb[idx];
  }
}

// ---------- fallback (round-1 single kernel) if ws is too small ----------
__global__ __launch_bounds__(NTH) void fftconv_fallback(
    const float* __restrict__ x, const float* __restrict__ log_amp,
    const float* __restrict__ log_decay, const float* __restrict__ mix_logit,
    float* __restrict__ out) {
  __shared__ float2 Z[kZPad];
  const int row = blockIdx.x;
  const int d = row & (kD - 1);
  const int h = (row >> 6) & (kH - 1);
  const int b = row >> 10;
  const int t = threadIdx.x;
  const size_t rowoff = (size_t)b * kL * kC + (size_t)h * kD + (size_t)d;
  const float* xrow = x + rowoff;
  float* orow = out + rowoff;

  const float av = log_amp[h];
  const float dv = log_decay[h];
  const float amp = (av > 20.f) ? av : log1pf(__expf(av));
  const float dec = ((dv > 20.f) ? dv : log1pf(__expf(dv))) + 1e-4f;
  const float ampS = amp * (1.0f / (float)kM);
  const float ml = mix_logit[h];
  const float mix = 1.0f / (1.0f + __expf(-ml));
  const float omix = 1.0f - mix;

  for (int i = 0; i < kM / NTH; ++i) {
    int n = t + i * NTH;
    float2 z;
    if (n < kL / 2) {
      z.x = xrow[(size_t)(2 * n) * kC];
      z.y = xrow[(size_t)(2 * n + 1) * kC];
    } else {
      z = make_float2(0.f, 0.f);
    }
    Z[IDX(n)] = z;
  }
  __syncthreads();

  for (int Ls = kM; Ls >= 4; Ls >>= 2) {
    const int q = Ls >> 2;
    const float wstep = -6.283185307179586f / (float)Ls;
    for (int i = 0; i < kM / 4 / NTH; ++i) {
      int bt = t + i * NTH;
      int jj = bt & (q - 1);
      int base = ((bt - jj) << 2) + jj;
      float2 a = Z[IDX(base)], bb = Z[IDX(base + q)];
      float2 c = Z[IDX(base + 2 * q)], dd = Z[IDX(base + 3 * q)];
      float2 t0 = cadd(a, c), t1 = csub(a, c), t2 = cadd(bb, dd), t3 = csub(bb, dd);
      float2 u0 = cadd(t0, t2), u2 = csub(t0, t2);
      float2 it3 = cmuli(t3);
      float2 u1 = csub(t1, it3), u3 = cadd(t1, it3);
      float sn, cs;
      __sincosf(wstep * (float)jj, &sn, &cs);
      float2 w1 = make_float2(cs, sn);
      float2 w2 = cmul(w1, w1);
      float2 w3 = cmul(w2, w1);
      Z[IDX(base)] = u0;
      Z[IDX(base + q)] = cmul(u1, w1);
      Z[IDX(base + 2 * q)] = cmul(u2, w2);
      Z[IDX(base + 3 * q)] = cmul(u3, w3);
    }
    __syncthreads();
  }

  for (int i = 0; i <= kM / 2 / NTH; ++i) {
    int k = t + i * NTH;
    if (k > kM / 2) continue;
    if (k == 0) {
      float2 Z0 = Z[IDX(0)];
      float X0 = Z0.x + Z0.y;
      float XM = Z0.x - Z0.y;
      float2 f0 = filt_val(0.f, ampS, dec);
      float2 fM = filt_val((float)kM, ampS, dec);
      float Y0 = X0 * f0.x;
      float YM = XM * fM.x;
      Z[IDX(0)] = make_float2(0.5f * (Y0 + YM), 0.5f * (Y0 - YM));
    } else if (k == kM / 2) {
      unsigned p = dr4(kM / 2);
      float2 Zk = Z[IDX(p)];
      float2 f = filt_val((float)(kM / 2), ampS, dec);
      float2 Y = cmul(cconj(Zk), f);
      Z[IDX(p)] = cconj(Y);
    } else {
      unsigned pk = dr4((unsigned)k), pmk = dr4((unsigned)(kM - k));
      float2 Zk = Z[IDX(pk)], Zmk = Z[IDX(pmk)];
      float2 A = cscale(cadd(Zk, cconj(Zmk)), 0.5f);
      float2 Bv = cscale(csub(Zk, cconj(Zmk)), 0.5f);
      float sn, cs;
      __sincosf(-3.14159265358979323846f * (float)k / (float)kM, &sn, &cs);
      float2 tw = make_float2(cs, sn);
      float2 P = cmuli(cmul(tw, Bv));
      float2 Xk = csub(A, P);
      float2 Xmk = cconj(cadd(A, P));
      float2 Yk = cmul(Xk, filt_val((float)k, ampS, dec));
      float2 Ymk = cmul(Xmk, filt_val((float)(kM - k), ampS, dec));
      float2 Ev = cscale(cadd(Yk, cconj(Ymk)), 0.5f);
      float2 Ov = cscale(cmul(cconj(tw), csub(Yk, cconj(Ymk))), 0.5f);
      float2 iO = cmuli(Ov);
      Z[IDX(pk)] = cadd(Ev, iO);
      Z[IDX(pmk)] = cconj(csub(Ev, iO));
    }
  }
  __syncthreads();

  for (int Ls = 4; Ls <= kM; Ls <<= 2) {
    const int q = Ls >> 2;
    const float wstep = 6.283185307179586f / (float)Ls;
    for (int i = 0; i < kM / 4 / NTH; ++i) {
      int bt = t + i * NTH;
      int jj = bt & (q - 1);
      int base = ((bt - jj) << 2) + jj;
      float sn, cs;
      __sincosf(wstep * (float)jj, &sn, &cs);
      float2 w1 = make_float2(cs, sn);
      float2 w2 = cmul(w1, w1);
      float2 w3 = cmul(w2, w1);
      float2 a = Z[IDX(base)];
      float2 bb = cmul(Z[IDX(base + q)], w1);
      float2 c = cmul(Z[IDX(base + 2 * q)], w2);
      float2 dd = cmul(Z[IDX(base + 3 * q)], w3);
      float2 s0 = cadd(a, c), s1 = csub(a, c), s2 = cadd(bb, dd), s3 = csub(bb, dd);
      float2 is3 = cmuli(s3);
      Z[IDX(base)] = cadd(s0, s2);
      Z[IDX(base + 2 * q)] = csub(s0, s2);
      Z[IDX(base + q)] = cadd(s1, is3);
      Z[IDX(base + 3 * q)] = csub(s1, is3);
    }
    __syncthreads();
  }

  for (int i = 0; i < kL / 2 / NTH; ++i) {
    int n = t + i * NTH;
    float2 w = Z[IDX(n)];
    size_t i0 = (size_t)(2 * n) * kC;
    float x0 = xrow[i0];
    float x1 = xrow[i0 + kC];
    orow[i0] = mix * w.x + omix * x0;
    orow[i0 + kC] = mix * w.y + omix * x1;
  }
}

extern "C" void kernel_launch(void* const* d_in, const int* in_sizes, int n_in,
                              void* d_out, int out_size, void* d_ws, size_t ws_size,
                              hipStream_t stream) {
  const float* x = (const float*)d_in[0];
  const float* la = (const float*)d_in[1];
  const float* ld = (const float*)d_in[2];
  const float* ml = (const float*)d_in[3];
  float* out = (float*)d_out;
  const size_t ybytes = (size_t)kB * kC * kL * sizeof(float);          // 64 MiB
  const size_t tabbytes = (size_t)kH * 2048 * 4 * sizeof(float2);      // 1 MiB
  if (ws_size >= ybytes + tabbytes) {
    float* ws = (float*)d_ws;
    float2* tab = (float2*)((char*)d_ws + ybytes);
    build_table<<<dim3(8, kH), dim3(256), 0, stream>>>(la, ld, tab);
    transpose_fwd<<<dim3(kL / 32, kC / 32, kB), dim3(256), 0, stream>>>(x, ws);
    fft_rows<<<dim3(kB * kC), dim3(NTH), 0, stream>>>(ws, tab);
    mix_out<<<dim3(kL / 32, kC / 32, kB), dim3(256), 0, stream>>>(ws, x, ml, out);
  } else {
    fftconv_fallback<<<dim3(kB * kC), dim3(NTH), 0, stream>>>(x, la, ld, ml, out);
  }
}

// Round 4
// 133.601 us; speedup vs baseline: 3.2475x; 1.2304x over previous
//
#include <hip/hip_runtime.h>
#include <math.h>

namespace {
constexpr int kB = 4;
constexpr int kL = 4096;
constexpr int kH = 16;
constexpr int kD = 64;
constexpr int kC = kH * kD;       // 1024 channels
constexpr int kM = 4096;          // complex FFT length (rfft of 8192 via packing)
constexpr int NTH = 256;

// ---------------- scalar complex helpers (aux kernels) ----------------
__device__ __forceinline__ float2 cmul(float2 a, float2 b) {
  return make_float2(a.x * b.x - a.y * b.y, a.x * b.y + a.y * b.x);
}
__device__ __forceinline__ float2 cadd(float2 a, float2 b) { return make_float2(a.x + b.x, a.y + b.y); }
__device__ __forceinline__ float2 csub(float2 a, float2 b) { return make_float2(a.x - b.x, a.y - b.y); }
__device__ __forceinline__ float2 cconj(float2 a) { return make_float2(a.x, -a.y); }
__device__ __forceinline__ float2 cmuli(float2 a) { return make_float2(-a.y, a.x); }  // i*a
__device__ __forceinline__ float2 cscale(float2 a, float s) { return make_float2(a.x * s, a.y * s); }

// ---------------- packed-FP32 complex helpers (fft_rows) ----------------
typedef float cplx __attribute__((ext_vector_type(2)));

__device__ __forceinline__ cplx pk_add(cplx a, cplx b) {
  cplx r;
  asm("v_pk_add_f32 %0, %1, %2" : "=v"(r) : "v"(a), "v"(b));
  return r;
}
__device__ __forceinline__ cplx pk_sub(cplx a, cplx b) {
  cplx r;
  asm("v_pk_add_f32 %0, %1, %2 neg_lo:[0,1] neg_hi:[0,1]" : "=v"(r) : "v"(a), "v"(b));
  return r;
}
// a + i*b = (a.x - b.y, a.y + b.x)
__device__ __forceinline__ cplx pk_addpi(cplx a, cplx b) {
  cplx r;
  asm("v_pk_add_f32 %0, %1, %2 op_sel:[0,1] op_sel_hi:[1,0] neg_lo:[0,1]" : "=v"(r) : "v"(a), "v"(b));
  return r;
}
// a - i*b = (a.x + b.y, a.y - b.x)
__device__ __forceinline__ cplx pk_addmi(cplx a, cplx b) {
  cplx r;
  asm("v_pk_add_f32 %0, %1, %2 op_sel:[0,1] op_sel_hi:[1,0] neg_hi:[0,1]" : "=v"(r) : "v"(a), "v"(b));
  return r;
}
// complex multiply: 2 VOP3P ops
__device__ __forceinline__ cplx pk_cmul(cplx a, cplx b) {
  cplx t, r;
  // t = (a.x*b.x, a.x*b.y)
  asm("v_pk_mul_f32 %0, %1, %2 op_sel:[0,0] op_sel_hi:[0,1]" : "=v"(t) : "v"(a), "v"(b));
  // r = (a.y*(-b.y) + t.lo, a.y*b.x + t.hi)
  asm("v_pk_fma_f32 %0, %1, %2, %3 op_sel:[1,1,0] op_sel_hi:[1,0,1] neg_lo:[0,1,0]"
      : "=v"(r) : "v"(a), "v"(b), "v"(t));
  return r;
}

// base-4 digit reversal of a 12-bit index (fallback kernel only)
__device__ __forceinline__ unsigned dr4(unsigned p) {
  unsigned r = __brev(p) >> 20;
  return ((r & 0x555u) << 1) | ((r >> 1) & 0x555u);
}
// base-16 digit reversal of a 12-bit index
__device__ __forceinline__ unsigned dr16(unsigned p) {
  return ((p & 15u) << 8) | (p & 0xF0u) | (p >> 8);
}
// LDS swizzle (cplx index space)
__device__ __forceinline__ int SW(int i) { return i ^ ((i >> 4) & 15); }
// after in-register DFT16, X[k] lives at register slot POS(k)
#define POS(k) ((((k) & 3) << 2) | ((k) >> 2))

// fallback-kernel padding
__device__ __forceinline__ int IDX(int i) { return i + (i >> 4); }
constexpr int kZPad = kM + (kM >> 4);

// filt[k] = amp * (1 + i k)^(-dec), with 1/M ifft scale folded into ampS
__device__ __forceinline__ float2 filt_val(float k, float ampS, float dec) {
  float mag = ampS * __expf(-0.5f * dec * log1pf(k * k));
  float ph = -dec * atanf(k);
  float s, c;
  __sincosf(ph, &s, &c);
  return make_float2(mag * c, mag * s);
}

// ---- fully-unrolled 16-point DFT in registers (packed-FP32) ----
// S = -1 forward, +1 inverse (unnormalized). HZ: inputs r[8..15] treated as 0.
// Output X[k] at slot POS(k).
template <int S, bool HZ>
__device__ __forceinline__ void fft16(cplx r[16]) {
  constexpr float C1 = 0.92387953251128674f;
  constexpr float S1 = 0.38268343236508978f;
  constexpr float R2 = 0.70710678118654752f;
  const float sg = (float)S;
  const cplx W1 = {C1, sg * S1};
  const cplx W2 = {R2, sg * R2};
  const cplx W3 = {S1, sg * C1};
  const cplx W6 = {-R2, sg * R2};
  const cplx W9 = {-C1, -sg * S1};
  // level 1: DFT4 over n1 on slots {n2, n2+4, n2+8, n2+12}; twiddle W16^{n2*k1};
  // store b[k1,n2] at slot n2 + 4*k1
#pragma unroll
  for (int n2 = 0; n2 < 4; ++n2) {
    cplx t0, t1, t2, t3;
    if (HZ) {
      t0 = r[n2]; t1 = r[n2]; t2 = r[n2 + 4]; t3 = r[n2 + 4];
    } else {
      cplx a0 = r[n2], a1 = r[n2 + 4], a2 = r[n2 + 8], a3 = r[n2 + 12];
      t0 = pk_add(a0, a2); t1 = pk_sub(a0, a2); t2 = pk_add(a1, a3); t3 = pk_sub(a1, a3);
    }
    // u1 = t1 + S*i*t3, u3 = t1 - S*i*t3
    cplx u0 = pk_add(t0, t2);
    cplx u2 = pk_sub(t0, t2);
    cplx u1 = (S < 0) ? pk_addmi(t1, t3) : pk_addpi(t1, t3);
    cplx u3 = (S < 0) ? pk_addpi(t1, t3) : pk_addmi(t1, t3);
    if (n2 == 0) { r[0] = u0; r[4] = u1; r[8] = u2; r[12] = u3; }
    if (n2 == 1) { r[1] = u0; r[5] = pk_cmul(u1, W1); r[9] = pk_cmul(u2, W2); r[13] = pk_cmul(u3, W3); }
    if (n2 == 2) {
      r[2] = u0; r[6] = pk_cmul(u1, W2);
      cplx m;  // u2 * (S*i)^... W16^4 = S*i branch: fwd -i*u2, inv +i*u2
      if (S < 0) { m.x = u2.y; m.y = -u2.x; } else { m.x = -u2.y; m.y = u2.x; }
      r[10] = m;
      r[14] = pk_cmul(u3, W6);
    }
    if (n2 == 3) { r[3] = u0; r[7] = pk_cmul(u1, W3); r[11] = pk_cmul(u2, W6); r[15] = pk_cmul(u3, W9); }
  }
  // level 2: DFT4 over n2 on slots {4s..4s+3}; X[k2*4+s] -> slot 4s+k2
#pragma unroll
  for (int s = 0; s < 4; ++s) {
    cplx b0 = r[4 * s], b1 = r[4 * s + 1], b2 = r[4 * s + 2], b3 = r[4 * s + 3];
    cplx t0 = pk_add(b0, b2), t1 = pk_sub(b0, b2), t2 = pk_add(b1, b3), t3 = pk_sub(b1, b3);
    r[4 * s] = pk_add(t0, t2);
    r[4 * s + 2] = pk_sub(t0, t2);
    r[4 * s + 1] = (S < 0) ? pk_addmi(t1, t3) : pk_addpi(t1, t3);
    r[4 * s + 3] = (S < 0) ? pk_addpi(t1, t3) : pk_addmi(t1, t3);
  }
}

// pointwise pair map (verified algebra), used only by build_table
__device__ __forceinline__ void pw_pair(float2 Zk, float2 Zmk, int k, float ampS, float dec,
                                        float2* Wk, float2* Wmk) {
  float2 A = cscale(cadd(Zk, cconj(Zmk)), 0.5f);
  float2 Bv = cscale(csub(Zk, cconj(Zmk)), 0.5f);
  float sn, cs;
  __sincosf(-3.14159265358979323846f * (float)k / (float)kM, &sn, &cs);
  float2 tw = make_float2(cs, sn);
  float2 P = cmuli(cmul(tw, Bv));
  float2 Xk = csub(A, P);
  float2 Xmk = cconj(cadd(A, P));
  float2 Yk = cmul(Xk, filt_val((float)k, ampS, dec));
  float2 Ymk = cmul(Xmk, filt_val((float)(kM - k), ampS, dec));
  float2 Ev = cscale(cadd(Yk, cconj(Ymk)), 0.5f);
  float2 Ov = cscale(cmul(cconj(tw), csub(Yk, cconj(Ymk))), 0.5f);
  float2 iO = cmuli(Ov);
  *Wk = cadd(Ev, iO);
  *Wmk = cconj(csub(Ev, iO));
}
}  // namespace

// ---------- pass 0: per-(h,k) 2x2 complex coefficient table ----------
__global__ __launch_bounds__(256) void build_table(const float* __restrict__ la,
                                                   const float* __restrict__ ld,
                                                   float2* __restrict__ tab) {
  int k = blockIdx.x * 256 + threadIdx.x;  // 0..2047
  int h = blockIdx.y;
  float av = la[h], dv = ld[h];
  float amp = (av > 20.f) ? av : log1pf(__expf(av));
  float dec = ((dv > 20.f) ? dv : log1pf(__expf(dv))) + 1e-4f;
  float ampS = amp * (1.0f / (float)kM);
  float2* e = tab + ((size_t)h * 2048 + k) * 4;
  if (k == 0) {
    float F0 = filt_val(0.f, ampS, dec).x;
    float FM = filt_val((float)kM, ampS, dec).x;
    e[0] = make_float2(0.5f * (F0 + FM), 0.5f * (F0 - FM));
    e[1] = make_float2(0.5f * (F0 - FM), 0.5f * (F0 + FM));
    e[2] = cconj(filt_val((float)(kM / 2), ampS, dec));
    e[3] = make_float2(0.f, 0.f);
  } else {
    float2 a, b, g, d;
    pw_pair(make_float2(1.f, 0.f), make_float2(0.f, 0.f), k, ampS, dec, &a, &g);
    pw_pair(make_float2(0.f, 0.f), make_float2(1.f, 0.f), k, ampS, dec, &b, &d);
    e[0] = a; e[1] = b; e[2] = g; e[3] = d;
  }
}

// ---------- pass 1: transpose x (B, L, C) -> ws (B, C, L), coalesced ----------
__global__ __launch_bounds__(256) void transpose_fwd(const float* __restrict__ in,
                                                     float* __restrict__ outp) {
  __shared__ float T[32][33];
  const int b = blockIdx.z;
  const int r0 = blockIdx.x * 32;  // l
  const int c0 = blockIdx.y * 32;  // c
  const float* ib = in + (size_t)b * kL * kC;
  float* ob = outp + (size_t)b * kC * kL;
  const int tx = threadIdx.x & 31, ty = threadIdx.x >> 5;
  for (int i = 0; i < 32; i += 8)
    T[ty + i][tx] = ib[(size_t)(r0 + ty + i) * kC + c0 + tx];
  __syncthreads();
  for (int i = 0; i < 32; i += 8)
    ob[(size_t)(c0 + ty + i) * kL + r0 + tx] = T[tx][ty + i];
}

// ---------- pass 2: per-row FFT conv (16^3 register radix-16, packed math) ----------
__global__ __launch_bounds__(NTH) void fft_rows(float* __restrict__ ws,
                                                const float2* __restrict__ tab) {
  __shared__ cplx Z[kM];  // exactly 32 KB
  const int row = blockIdx.x;  // b*1024 + c
  const int h = (row >> 6) & (kH - 1);
  const int t = threadIdx.x;
  cplx* xrow = (cplx*)(ws + (size_t)row * kL);  // 2048 cplx

  cplx r[16];
  const int swt = t ^ ((t >> 4) & 15);

  // ---- F1: global load (coalesced), DFT16 over n1, twiddle W4096^{t*k1} ----
#pragma unroll
  for (int j = 0; j < 8; ++j) r[j] = xrow[t + 256 * j];
  fft16<-1, true>(r);
  {
    float sn, cs;
    __sincosf(-6.283185307179586f * (float)t / 4096.f, &sn, &cs);
    cplx w = {cs, sn}, cur = w;
    r[POS(1)] = pk_cmul(r[POS(1)], cur);
#pragma unroll
    for (int k1 = 2; k1 < 16; ++k1) { cur = pk_cmul(cur, w); r[POS(k1)] = pk_cmul(r[POS(k1)], cur); }
    cplx* Zb = &Z[swt];
#pragma unroll
    for (int k1 = 0; k1 < 16; ++k1) Zb[k1 << 8] = r[POS(k1)];
  }
  __syncthreads();

  // ---- F2: DFT16 over m1 (stride 16), twiddle W256^{m2*j1} ----
  {
    const int g = t >> 4, m2 = t & 15;
    const int base = g << 8;
#pragma unroll
    for (int m1 = 0; m1 < 16; ++m1) r[m1] = Z[base + (m1 << 4) + (m2 ^ m1)];
    fft16<-1, false>(r);
    float sn, cs;
    __sincosf(-6.283185307179586f * (float)m2 / 256.f, &sn, &cs);
    cplx w = {cs, sn}, cur = w;
    r[POS(1)] = pk_cmul(r[POS(1)], cur);
#pragma unroll
    for (int j1 = 2; j1 < 16; ++j1) { cur = pk_cmul(cur, w); r[POS(j1)] = pk_cmul(r[POS(j1)], cur); }
#pragma unroll
    for (int j1 = 0; j1 < 16; ++j1) Z[base + (j1 << 4) + (m2 ^ j1)] = r[POS(j1)];
  }
  __syncthreads();

  // ---- F3: DFT16 over m2 (contiguous 16), no twiddle ----
  {
    const int g = t >> 4, j1 = t & 15;
    const int base = (g << 8) + (j1 << 4);
#pragma unroll
    for (int m2 = 0; m2 < 16; ++m2) r[m2] = Z[base + (m2 ^ j1)];
    fft16<-1, false>(r);
#pragma unroll
    for (int j2 = 0; j2 < 16; ++j2) Z[base + (j2 ^ j1)] = r[POS(j2)];
  }
  __syncthreads();

  // ---- pointwise via table; position p holds bin dr16(p) ----
  for (int i = 0; i < 16; ++i) {
    int p = t + (i << 8);
    unsigned k = dr16((unsigned)p);
    if (k > 2048u) continue;
    if (k == 0u) {  // p == 0
      const float4* tp = (const float4*)(tab + (size_t)h * 2048 * 4);
      float4 q0 = tp[0];
      cplx Z0 = Z[0];
      cplx o; o.x = q0.x * Z0.x + q0.y * Z0.y; o.y = q0.z * Z0.x + q0.w * Z0.y;
      Z[0] = o;
    } else if (k == 2048u) {  // p == 8
      const float4* tp = (const float4*)(tab + (size_t)h * 2048 * 4);
      float4 q1 = tp[1];
      int sp = SW(p);
      cplx f; f.x = q1.x; f.y = q1.y;
      Z[sp] = pk_cmul(f, Z[sp]);
    } else {
      int p2 = (int)dr16(4096u - k);
      int sp = SW(p), sp2 = SW(p2);
      cplx Zk = Z[sp], Zmk = Z[sp2];
      const float4* tp = (const float4*)(tab + ((size_t)h * 2048 + k) * 4);
      float4 q0 = tp[0], q1 = tp[1];
      cplx e0 = {q0.x, q0.y}, e1 = {q0.z, q0.w};
      cplx e2 = {q1.x, q1.y}, e3 = {q1.z, q1.w};
      cplx cZk = {Zk.x, -Zk.y}, cZmk = {Zmk.x, -Zmk.y};
      Z[sp] = pk_add(pk_cmul(e0, Zk), pk_cmul(e1, cZmk));
      Z[sp2] = pk_add(pk_cmul(e2, cZk), pk_cmul(e3, Zmk));
    }
  }
  __syncthreads();

  // ---- I1: IDFT16 over j2 (contiguous 16), twiddle e^{+2pi i j1*m2/256} ----
  {
    const int k1 = t >> 4, j1 = t & 15;
    const int base = (k1 << 8) + (j1 << 4);
#pragma unroll
    for (int j2 = 0; j2 < 16; ++j2) r[j2] = Z[base + (j2 ^ j1)];
    fft16<1, false>(r);
    float sn, cs;
    __sincosf(6.283185307179586f * (float)j1 / 256.f, &sn, &cs);
    cplx w = {cs, sn}, cur = w;
    r[POS(1)] = pk_cmul(r[POS(1)], cur);
#pragma unroll
    for (int m2 = 2; m2 < 16; ++m2) { cur = pk_cmul(cur, w); r[POS(m2)] = pk_cmul(r[POS(m2)], cur); }
#pragma unroll
    for (int m2 = 0; m2 < 16; ++m2) Z[base + (m2 ^ j1)] = r[POS(m2)];
  }
  __syncthreads();

  // ---- I2: IDFT16 over j1 (stride 16), twiddle e^{+2pi i k1*(m1*16+m2)/4096} ----
  {
    const int k1 = t >> 4, m2 = t & 15;
#pragma unroll
    for (int j1 = 0; j1 < 16; ++j1) r[j1] = Z[(k1 << 8) + (j1 << 4) + (m2 ^ j1)];
    fft16<1, false>(r);
    float sn, cs;
    __sincosf(6.283185307179586f * (float)(k1 * m2) / 4096.f, &sn, &cs);
    cplx cur = {cs, sn};
    __sincosf(6.283185307179586f * (float)k1 / 256.f, &sn, &cs);
    cplx w = {cs, sn};
    r[POS(0)] = pk_cmul(r[POS(0)], cur);
#pragma unroll
    for (int m1 = 1; m1 < 16; ++m1) { cur = pk_cmul(cur, w); r[POS(m1)] = pk_cmul(r[POS(m1)], cur); }
#pragma unroll
    for (int m1 = 0; m1 < 16; ++m1) Z[(k1 << 8) + (m1 << 4) + (m2 ^ m1)] = r[POS(m1)];
  }
  __syncthreads();

  // ---- I3: IDFT16 over k1 (stride 256), direct coalesced global store ----
  {
    cplx* Zb = &Z[swt];
#pragma unroll
    for (int k1 = 0; k1 < 16; ++k1) r[k1] = Zb[k1 << 8];
    fft16<1, false>(r);
#pragma unroll
    for (int n1 = 0; n1 < 8; ++n1) xrow[(n1 << 8) + t] = r[POS(n1)];
  }
}

// ---------- pass 3: transpose back ws (B, C, L) -> out (B, L, C) + mix ----------
__global__ __launch_bounds__(256) void mix_out(const float* __restrict__ yT,
                                               const float* __restrict__ x,
                                               const float* __restrict__ mix_logit,
                                               float* __restrict__ outp) {
  __shared__ float T[32][33];
  const int b = blockIdx.z;
  const int r0 = blockIdx.x * 32;  // l
  const int c0 = blockIdx.y * 32;  // c
  const int h = c0 >> 6;
  const float ml = mix_logit[h];
  const float mix = 1.0f / (1.0f + __expf(-ml));
  const float omix = 1.0f - mix;
  const float* yb = yT + (size_t)b * kC * kL;
  const float* xb = x + (size_t)b * kL * kC;
  float* ob = outp + (size_t)b * kL * kC;
  const int tx = threadIdx.x & 31, ty = threadIdx.x >> 5;
  for (int i = 0; i < 32; i += 8)
    T[ty + i][tx] = yb[(size_t)(c0 + ty + i) * kL + r0 + tx];
  __syncthreads();
  for (int i = 0; i < 32; i += 8) {
    size_t idx = (size_t)(r0 + ty + i) * kC + c0 + tx;
    ob[idx] = mix * T[tx][ty + i] + omix * xb[idx];
  }
}

// ---------- fallback (round-1 single kernel) if ws is too small ----------
__global__ __launch_bounds__(NTH) void fftconv_fallback(
    const float* __restrict__ x, const float* __restrict__ log_amp,
    const float* __restrict__ log_decay, const float* __restrict__ mix_logit,
    float* __restrict__ out) {
  __shared__ float2 Z[kZPad];
  const int row = blockIdx.x;
  const int d = row & (kD - 1);
  const int h = (row >> 6) & (kH - 1);
  const int b = row >> 10;
  const int t = threadIdx.x;
  const size_t rowoff = (size_t)b * kL * kC + (size_t)h * kD + (size_t)d;
  const float* xrow = x + rowoff;
  float* orow = out + rowoff;

  const float av = log_amp[h];
  const float dv = log_decay[h];
  const float amp = (av > 20.f) ? av : log1pf(__expf(av));
  const float dec = ((dv > 20.f) ? dv : log1pf(__expf(dv))) + 1e-4f;
  const float ampS = amp * (1.0f / (float)kM);
  const float ml = mix_logit[h];
  const float mix = 1.0f / (1.0f + __expf(-ml));
  const float omix = 1.0f - mix;

  for (int i = 0; i < kM / NTH; ++i) {
    int n = t + i * NTH;
    float2 z;
    if (n < kL / 2) {
      z.x = xrow[(size_t)(2 * n) * kC];
      z.y = xrow[(size_t)(2 * n + 1) * kC];
    } else {
      z = make_float2(0.f, 0.f);
    }
    Z[IDX(n)] = z;
  }
  __syncthreads();

  for (int Ls = kM; Ls >= 4; Ls >>= 2) {
    const int q = Ls >> 2;
    const float wstep = -6.283185307179586f / (float)Ls;
    for (int i = 0; i < kM / 4 / NTH; ++i) {
      int bt = t + i * NTH;
      int jj = bt & (q - 1);
      int base = ((bt - jj) << 2) + jj;
      float2 a = Z[IDX(base)], bb = Z[IDX(base + q)];
      float2 c = Z[IDX(base + 2 * q)], dd = Z[IDX(base + 3 * q)];
      float2 t0 = cadd(a, c), t1 = csub(a, c), t2 = cadd(bb, dd), t3 = csub(bb, dd);
      float2 u0 = cadd(t0, t2), u2 = csub(t0, t2);
      float2 it3 = cmuli(t3);
      float2 u1 = csub(t1, it3), u3 = cadd(t1, it3);
      float sn, cs;
      __sincosf(wstep * (float)jj, &sn, &cs);
      float2 w1 = make_float2(cs, sn);
      float2 w2 = cmul(w1, w1);
      float2 w3 = cmul(w2, w1);
      Z[IDX(base)] = u0;
      Z[IDX(base + q)] = cmul(u1, w1);
      Z[IDX(base + 2 * q)] = cmul(u2, w2);
      Z[IDX(base + 3 * q)] = cmul(u3, w3);
    }
    __syncthreads();
  }

  for (int i = 0; i <= kM / 2 / NTH; ++i) {
    int k = t + i * NTH;
    if (k > kM / 2) continue;
    if (k == 0) {
      float2 Z0 = Z[IDX(0)];
      float X0 = Z0.x + Z0.y;
      float XM = Z0.x - Z0.y;
      float2 f0 = filt_val(0.f, ampS, dec);
      float2 fM = filt_val((float)kM, ampS, dec);
      float Y0 = X0 * f0.x;
      float YM = XM * fM.x;
      Z[IDX(0)] = make_float2(0.5f * (Y0 + YM), 0.5f * (Y0 - YM));
    } else if (k == kM / 2) {
      unsigned p = dr4(kM / 2);
      float2 Zk = Z[IDX(p)];
      float2 f = filt_val((float)(kM / 2), ampS, dec);
      float2 Y = cmul(cconj(Zk), f);
      Z[IDX(p)] = cconj(Y);
    } else {
      unsigned pk = dr4((unsigned)k), pmk = dr4((unsigned)(kM - k));
      float2 Zk = Z[IDX(pk)], Zmk = Z[IDX(pmk)];
      float2 A = cscale(cadd(Zk, cconj(Zmk)), 0.5f);
      float2 Bv = cscale(csub(Zk, cconj(Zmk)), 0.5f);
      float sn, cs;
      __sincosf(-3.14159265358979323846f * (float)k / (float)kM, &sn, &cs);
      float2 tw = make_float2(cs, sn);
      float2 P = cmuli(cmul(tw, Bv));
      float2 Xk = csub(A, P);
      float2 Xmk = cconj(cadd(A, P));
      float2 Yk = cmul(Xk, filt_val((float)k, ampS, dec));
      float2 Ymk = cmul(Xmk, filt_val((float)(kM - k), ampS, dec));
      float2 Ev = cscale(cadd(Yk, cconj(Ymk)), 0.5f);
      float2 Ov = cscale(cmul(cconj(tw), csub(Yk, cconj(Ymk))), 0.5f);
      float2 iO = cmuli(Ov);
      Z[IDX(pk)] = cadd(Ev, iO);
      Z[IDX(pmk)] = cconj(csub(Ev, iO));
    }
  }
  __syncthreads();

  for (int Ls = 4; Ls <= kM; Ls <<= 2) {
    const int q = Ls >> 2;
    const float wstep = 6.283185307179586f / (float)Ls;
    for (int i = 0; i < kM / 4 / NTH; ++i) {
      int bt = t + i * NTH;
      int jj = bt & (q - 1);
      int base = ((bt - jj) << 2) + jj;
      float sn, cs;
      __sincosf(wstep * (float)jj, &sn, &cs);
      float2 w1 = make_float2(cs, sn);
      float2 w2 = cmul(w1, w1);
      float2 w3 = cmul(w2, w1);
      float2 a = Z[IDX(base)];
      float2 bb = cmul(Z[IDX(base + q)], w1);
      float2 c = cmul(Z[IDX(base + 2 * q)], w2);
      float2 dd = cmul(Z[IDX(base + 3 * q)], w3);
      float2 s0 = cadd(a, c), s1 = csub(a, c), s2 = cadd(bb, dd), s3 = csub(bb, dd);
      float2 is3 = cmuli(s3);
      Z[IDX(base)] = cadd(s0, s2);
      Z[IDX(base + 2 * q)] = csub(s0, s2);
      Z[IDX(base + q)] = cadd(s1, is3);
      Z[IDX(base + 3 * q)] = csub(s1, is3);
    }
    __syncthreads();
  }

  for (int i = 0; i < kL / 2 / NTH; ++i) {
    int n = t + i * NTH;
    float2 w = Z[IDX(n)];
    size_t i0 = (size_t)(2 * n) * kC;
    float x0 = xrow[i0];
    float x1 = xrow[i0 + kC];
    orow[i0] = mix * w.x + omix * x0;
    orow[i0 + kC] = mix * w.y + omix * x1;
  }
}

extern "C" void kernel_launch(void* const* d_in, const int* in_sizes, int n_in,
                              void* d_out, int out_size, void* d_ws, size_t ws_size,
                              hipStream_t stream) {
  const float* x = (const float*)d_in[0];
  const float* la = (const float*)d_in[1];
  const float* ld = (const float*)d_in[2];
  const float* ml = (const float*)d_in[3];
  float* out = (float*)d_out;
  const size_t ybytes = (size_t)kB * kC * kL * sizeof(float);          // 64 MiB
  const size_t tabbytes = (size_t)kH * 2048 * 4 * sizeof(float2);      // 1 MiB
  if (ws_size >= ybytes + tabbytes) {
    float* ws = (float*)d_ws;
    float2* tab = (float2*)((char*)d_ws + ybytes);
    build_table<<<dim3(8, kH), dim3(256), 0, stream>>>(la, ld, tab);
    transpose_fwd<<<dim3(kL / 32, kC / 32, kB), dim3(256), 0, stream>>>(x, ws);
    fft_rows<<<dim3(kB * kC), dim3(NTH), 0, stream>>>(ws, tab);
    mix_out<<<dim3(kL / 32, kC / 32, kB), dim3(256), 0, stream>>>(ws, x, ml, out);
  } else {
    fftconv_fallback<<<dim3(kB * kC), dim3(NTH), 0, stream>>>(x, la, ld, ml, out);
  }
}